// Round 4
// baseline (674.716 us; speedup 1.0000x reference)
//
#include <hip/hip_runtime.h>
#include <hip/hip_bf16.h>
#include <math.h>

#define B_   1024
#define N_   200
#define NR_  208      // padded rows (13 x 16)
#define NT_  13
#define E_   256
#define R_   256
#define K6_  1536

typedef __attribute__((ext_vector_type(8))) short bf16x8;
typedef __attribute__((ext_vector_type(4))) float f32x4;

__device__ __forceinline__ unsigned short f2bf(float f) {
  unsigned int u = __float_as_uint(f);
  u += 0x7fffu + ((u >> 16) & 1u);          // RNE
  return (unsigned short)(u >> 16);
}

// HW packed cvt (v_cvt_pk_bf16_f32), RNE — bit-identical to f2bf for finite vals
__device__ __forceinline__ unsigned int pk_bf(float lo, float hi) {
  float2 t; t.x = lo; t.y = hi;
  __hip_bfloat162 h = __float22bfloat162_rn(t);
  unsigned int u;
  __builtin_memcpy(&u, &h, 4);
  return u;
}

__device__ __forceinline__ float gelu_exact(float x) {
  return 0.5f * x * (1.f + erff(x * 0.70710678118654752f));
}

// ---------------- cast rel_w and sp_w to bf16 in ws ----------------
__global__ __launch_bounds__(256) void k_cast(const float* __restrict__ rel_w,
                                              const float* __restrict__ sp_w,
                                              unsigned short* __restrict__ rw_bf,
                                              unsigned short* __restrict__ spw_bf) {
  int idx = blockIdx.x * 256 + threadIdx.x;
  if (idx < E_ * R_) rw_bf[idx] = f2bf(rel_w[idx]);
  int j = idx - E_ * R_;
  if (j >= 0 && j < 3 * E_ * K6_) spw_bf[j] = f2bf(sp_w[j]);
}

// ------- k_prep: fused q_key -> (csq logits, wts) -> q_proj -> t(bf16) -------
__global__ __launch_bounds__(256) void k_prep(
    const float* __restrict__ r_emb, const float* __restrict__ rel_w,
    const float* __restrict__ csq_w, const float* __restrict__ csq_b,
    const float* __restrict__ csl_w, const float* __restrict__ csl_b,
    const float* __restrict__ attn_w,
    unsigned short* __restrict__ t_bf, float* __restrict__ wts) {
  __shared__ __align__(16) float re[4][256];
  __shared__ __align__(16) float qk[4][256];
  __shared__ __align__(16) float sqs[4][256];
  __shared__ __align__(16) float qp[3][4][256];
  __shared__ float lg[4][3];
  int b0 = blockIdx.x * 4;
  int tid = threadIdx.x;
  int e = tid;
#pragma unroll
  for (int i = 0; i < 4; ++i)
    re[i][tid] = r_emb[(size_t)(b0 + i) * 256 + tid];
  __syncthreads();
  {
    float qkv[4], sv[4];
#pragma unroll
    for (int i = 0; i < 4; ++i) { qkv[i] = 0.f; sv[i] = 0.f; }
    const float4* w4 = (const float4*)(rel_w) + (size_t)e * 64;
    const float4* c4 = (const float4*)(csq_w) + (size_t)e * 64;
    for (int r = 0; r < 64; ++r) {
      float4 w = w4[r];
      float4 c = c4[r];
#pragma unroll
      for (int i = 0; i < 4; ++i) {
        float4 x = ((const float4*)re[i])[r];
        qkv[i] += w.x * x.x + w.y * x.y + w.z * x.z + w.w * x.w;
        sv[i] += c.x * x.x + c.y * x.y + c.z * x.z + c.w * x.w;
      }
    }
    float cb = csq_b[e];
#pragma unroll
    for (int i = 0; i < 4; ++i) {
      qk[i][e] = qkv[i];
      sqs[i][e] = sv[i] + cb;
    }
  }
  __syncthreads();
  if (tid < 12) {
    int i = tid / 3, k = tid % 3;
    float acc = csl_b[k];
    for (int ee = 0; ee < 256; ++ee) acc += sqs[i][ee] * csl_w[k * 256 + ee];
    lg[i][k] = acc;
  }
  __syncthreads();
  if (tid < 4) {
    float l0 = lg[tid][0], l1 = lg[tid][1], l2 = lg[tid][2];
    float m = fmaxf(l0, fmaxf(l1, l2));
    float e0 = expf(l0 - m), e1 = expf(l1 - m), e2 = expf(l2 - m);
    float inv = 1.f / (e0 + e1 + e2);
    wts[(b0 + tid) * 4 + 0] = e0 * inv;
    wts[(b0 + tid) * 4 + 1] = e1 * inv;
    wts[(b0 + tid) * 4 + 2] = e2 * inv;
  }
  {
    float qpv[3][4];
#pragma unroll
    for (int s = 0; s < 3; ++s)
#pragma unroll
      for (int i = 0; i < 4; ++i) qpv[s][i] = 0.f;
#pragma unroll
    for (int s = 0; s < 3; ++s) {
      const float4* a4 = (const float4*)(attn_w) + ((size_t)s * 256 + e) * 64;
      for (int r = 0; r < 64; ++r) {
        float4 w = a4[r];
#pragma unroll
        for (int i = 0; i < 4; ++i) {
          float4 x = ((const float4*)qk[i])[r];
          qpv[s][i] += w.x * x.x + w.y * x.y + w.z * x.z + w.w * x.w;
        }
      }
    }
    __syncthreads();
#pragma unroll
    for (int s = 0; s < 3; ++s)
#pragma unroll
      for (int i = 0; i < 4; ++i) qp[s][i][e] = qpv[s][i];
  }
  __syncthreads();
  {
    int r = tid;
    float tacc[3][4];
#pragma unroll
    for (int s = 0; s < 3; ++s)
#pragma unroll
      for (int i = 0; i < 4; ++i) tacc[s][i] = 0.f;
    for (int e4 = 0; e4 < 64; ++e4) {
      float4 qv[3][4];
#pragma unroll
      for (int s = 0; s < 3; ++s)
#pragma unroll
        for (int i = 0; i < 4; ++i)
          qv[s][i] = ((const float4*)qp[s][i])[e4];
#pragma unroll
      for (int j = 0; j < 4; ++j) {
        float w = rel_w[(size_t)(e4 * 4 + j) * 256 + r];
#pragma unroll
        for (int s = 0; s < 3; ++s)
#pragma unroll
          for (int i = 0; i < 4; ++i) {
            float q = (j == 0) ? qv[s][i].x : (j == 1) ? qv[s][i].y
                      : (j == 2) ? qv[s][i].z : qv[s][i].w;
            tacc[s][i] = fmaf(q, w, tacc[s][i]);
          }
      }
    }
    // t as bf16, layout [b][s][r] — consumed as MFMA B-fragments in k1
#pragma unroll
    for (int s = 0; s < 3; ++s)
#pragma unroll
      for (int i = 0; i < 4; ++i)
        t_bf[((size_t)(b0 + i) * 3 + s) * 256 + r] = f2bf(tacc[s][i]);
  }
}

// ------------- K1: FLASH single-pass fused msgs-GEMM + PNA + online attn ----
// 1024 threads (16 waves), block = one b. Per tile: 8 ds_read_b128 feed TWO
// MFMAs each (msgs w/ bfr, logits w/ tfrag — logits duplicated per wave so
// softmax state is wave-local). Online-softmax rescale (running m per scale)
// removes the softmax phase + second pass. 1 barrier/tile, single data read.
__global__ __launch_bounds__(1024, 4) void k1_main(
    const float* __restrict__ nb_rel, const float* __restrict__ delta_t,
    const unsigned char* __restrict__ hm_raw, const float* __restrict__ e_emb,
    const float* __restrict__ p_lt1, const float* __restrict__ p_lt2,
    const float* __restrict__ p_sh, const float* __restrict__ p_lgm,
    const unsigned short* __restrict__ rw_bf, const unsigned short* __restrict__ t_bf,
    unsigned short* __restrict__ feats) {
  __shared__ __align__(16) struct {
    unsigned int a[2 * 16 * 132];  // 2 slots x 16 rows, row stride 264 bf16 (256+8 pad)
    float nmeta[NR_ * 12];         // [0..2]=mf*c [3]=off(0|1e4) [4..6]=c [7]=mf
  } sm;
  int b = blockIdx.x;
  int tid = threadIdx.x;
  int lane = tid & 63, wave = tid >> 6;
  int row16 = lane & 15, quad = lane >> 4;

  // ---- mask dtype detection: probe first 1024 bytes ----
  int hasNZoff = 0, hasFP = 0;
  {
    unsigned char cc = hm_raw[tid];
    if ((tid & 3) != 0 && cc != 0) {
      hasNZoff = 1;
      if (cc == 0x3Fu || cc == 0x80u) hasFP = 1;
    }
  }
  int cntNZ = __syncthreads_count(hasNZoff);
  int cntFP = __syncthreads_count(hasFP);
  int mmode = (cntNZ == 0) ? 0 : (cntFP > 0 ? 2 : 1);  // 0=int32 1=bool 2=f32

  float tau1 = __expf(p_lt1[0]);
  float tau2 = __expf(p_lt2[0]) + tau1;
  float sharp = fminf(fmaxf(p_sh[0], 0.1f), 5.0f);
  float gamma = __expf(p_lgm[0]);

  bool mk = false;
  if (tid < NR_) {
    float mf = 0.f, c0 = 0.f, c1 = 0.f, c2 = 0.f;
    if (tid < N_) {
      size_t mi = (size_t)b * N_ + tid;
      if (mmode == 0)      mk = ((const int*)hm_raw)[mi] != 0;
      else if (mmode == 1) mk = hm_raw[mi] != 0;
      else                 mk = ((const float*)hm_raw)[mi] != 0.f;
      float dt = delta_t[mi];
      mf = mk ? 1.f : 0.f;
      float decay = __expf(-gamma * fmaxf(dt, 0.f));
      float wf = 1.f / (1.f + __expf(sharp * (dt - tau1)));
      float wc = 1.f / (1.f + __expf(-sharp * (dt - tau2)));
      float wm = fmaxf(1.f - wf - wc, 0.f);
      c0 = decay * wf; c1 = decay * wm; c2 = decay * wc;
    }
    f32x4 w0, w1;
    w0[0] = mf * c0; w0[1] = mf * c1; w0[2] = mf * c2; w0[3] = mk ? 0.f : 1e4f;
    w1[0] = c0; w1[1] = c1; w1[2] = c2; w1[3] = mf;
    *(f32x4*)&sm.nmeta[tid * 12]     = w0;
    *(f32x4*)&sm.nmeta[tid * 12 + 4] = w1;
  }
  int cnt = __syncthreads_count(mk ? 1 : 0);
  float nvf = fmaxf((float)cnt, 1.f);
  bool allinv = (cnt == 0);

  const float* srcw = nb_rel + (size_t)b * N_ * 256 + lane * 4;

  // t B-fragments (every wave; duplicates logit MFMA -> wave-local softmax)
  bf16x8 tfrag[8];
  {
    int sr = (row16 < 3) ? row16 : 0;
    const unsigned short* tb = t_bf + ((size_t)b * 3 + sr) * 256 + quad * 8;
    bf16x8 zer = {0, 0, 0, 0, 0, 0, 0, 0};
#pragma unroll
    for (int ks = 0; ks < 8; ++ks) {
      bf16x8 tv = *(const bf16x8*)(tb + ks * 32);
      tfrag[ks] = (row16 < 3) ? tv : zer;
    }
  }
  // rel_w B-fragments (wave owns 16 e-cols)
  bf16x8 bfr[8];
  {
    int e = wave * 16 + row16;
#pragma unroll
    for (int ks = 0; ks < 8; ++ks)
      bfr[ks] = *(const bf16x8*)(rw_bf + (size_t)e * 256 + ks * 32 + quad * 8);
  }

  // e_emb tail copy, spread across first 256 threads (before the loop)
  if (tid < 256) {
    unsigned short v = f2bf(e_emb[(size_t)b * 256 + tid]);
    feats[((size_t)0 * B_ + b) * K6_ + 1280 + tid] = v;
    feats[((size_t)1 * B_ + b) * K6_ + 1280 + tid] = v;
    feats[((size_t)2 * B_ + b) * K6_ + 1280 + tid] = v;
  }

  // prologue: stage tile 0 -> slot 0 (wave w stages row w; rows 0..15 < N_)
  {
    float4 x = *(const float4*)(srcw + (size_t)wave * 256);
    uint2 pk;
    pk.x = pk_bf(x.x, x.y);
    pk.y = pk_bf(x.z, x.w);
    *(uint2*)&sm.a[wave * 132 + lane * 2] = pk;
  }
  __syncthreads();

  // online-softmax state + stats accumulators
  float m_run[3] = {-1e30f, -1e30f, -1e30f};
  float s_mean[3], s_mx[3], s_mn[3], s_sq[3], s_av[3], s_ss[3];
#pragma unroll
  for (int s = 0; s < 3; ++s) {
    s_mean[s] = 0.f; s_mx[s] = -1e30f; s_mn[s] = 1e30f;
    s_sq[s] = 0.f; s_av[s] = 0.f; s_ss[s] = 0.f;
  }

  int sr = (row16 < 3) ? row16 : 0;
  int srcb = quad << 4;

  for (int t = 0; t < NT_; ++t) {
    float4 xn;
    if (t < NT_ - 1) {
      int n = (t + 1) * 16 + wave;
      int gn = (n < N_) ? n : (N_ - 1);
      xn = *(const float4*)(srcw + (size_t)gn * 256);
    }
    const unsigned int* sa = &sm.a[(t & 1) * 2112];
    f32x4 am, al;
    am[0] = 0.f; am[1] = 0.f; am[2] = 0.f; am[3] = 0.f;
    al[0] = 0.f; al[1] = 0.f; al[2] = 0.f; al[3] = 0.f;
#pragma unroll
    for (int ks = 0; ks < 8; ++ks) {
      bf16x8 af = *(const bf16x8*)&sa[row16 * 132 + ks * 16 + quad * 4];
      am = __builtin_amdgcn_mfma_f32_16x16x32_bf16(af, bfr[ks], am, 0, 0, 0);
      al = __builtin_amdgcn_mfma_f32_16x16x32_bf16(af, tfrag[ks], al, 0, 0, 0);
    }
    int rowbase = t * 16 + quad * 4;
    // logits for this wave's quad rows (valid on lanes row16<3; sr-clamped else)
    float l[4];
#pragma unroll
    for (int rg = 0; rg < 4; ++rg) {
      int row = rowbase + rg;
      float cw  = sm.nmeta[row * 12 + 4 + sr];
      float mfv = sm.nmeta[row * 12 + 7];
      float lv = cw * al[rg] * 0.0625f;
      lv = (mfv > 0.5f) ? lv : -1e4f;
      if (allinv) lv = (row < N_) ? 0.f : -1e4f;
      l[rg] = lv;
    }
    // tile max per scale (rows live across quads; reduce on s-lanes, broadcast)
    float tm = fmaxf(fmaxf(l[0], l[1]), fmaxf(l[2], l[3]));
    tm = fmaxf(tm, __shfl_xor(tm, 16, 64));
    tm = fmaxf(tm, __shfl_xor(tm, 32, 64));
    float nmv0 = __shfl(tm, 0, 64);
    float nmv1 = __shfl(tm, 1, 64);
    float nmv2 = __shfl(tm, 2, 64);
    float f[3];
    {
      float nmv[3] = {nmv0, nmv1, nmv2};
#pragma unroll
      for (int s = 0; s < 3; ++s) {
        float nn = fmaxf(m_run[s], nmv[s]);
        f[s] = __expf(m_run[s] - nn);
        m_run[s] = nn;
        s_av[s] *= f[s];
        s_ss[s] *= f[s];
      }
    }
    // unnormalized p on the logit lanes
    float nmown = (row16 == 0) ? m_run[0] : ((row16 == 1) ? m_run[1] : m_run[2]);
    float p[4];
#pragma unroll
    for (int rg = 0; rg < 4; ++rg) p[rg] = __expf(l[rg] - nmown);
    // stats + attn accumulation (p broadcast per row from this quad's s-lanes)
#pragma unroll
    for (int rg = 0; rg < 4; ++rg) {
      float p0 = __shfl(p[rg], srcb + 0, 64);
      float p1 = __shfl(p[rg], srcb + 1, 64);
      float p2 = __shfl(p[rg], srcb + 2, 64);
      const float* nmp = &sm.nmeta[(size_t)(rowbase + rg) * 12];
      f32x4 w0 = *(const f32x4*)nmp;        // cm0 cm1 cm2 off
      f32x4 w1 = *(const f32x4*)(nmp + 4);  // c0  c1  c2  mf
      float mm = am[rg];
      float pv[3] = {p0, p1, p2};
#pragma unroll
      for (int s = 0; s < 3; ++s) {
        float vm = w0[s] * mm;
        s_mean[s] += vm;
        s_mx[s] = fmaxf(s_mx[s], vm);
        s_mn[s] = fminf(s_mn[s], fmaf(w0[s], mm, w0[3]));
        float cv = fminf(fmaxf(vm, -10.f), 10.f);
        s_sq[s] = fmaf(cv, cv, s_sq[s]);
        s_av[s] = fmaf(pv[s] * w1[s], mm, s_av[s]);
        s_ss[s] += pv[s];
      }
    }
    if (t < NT_ - 1) {
      uint2 pk;
      pk.x = pk_bf(xn.x, xn.y);
      pk.y = pk_bf(xn.z, xn.w);
      *(uint2*)&sm.a[((t + 1) & 1) * 2112 + wave * 132 + lane * 2] = pk;
    }
    __syncthreads();
  }

  // ---- reduce across quads, write feats (bf16) ----
#pragma unroll
  for (int s = 0; s < 3; ++s) {
    float vmean = s_mean[s];
    vmean += __shfl_xor(vmean, 16, 64); vmean += __shfl_xor(vmean, 32, 64);
    float vmx = s_mx[s];
    vmx = fmaxf(vmx, __shfl_xor(vmx, 16, 64)); vmx = fmaxf(vmx, __shfl_xor(vmx, 32, 64));
    float vmn = s_mn[s];
    vmn = fminf(vmn, __shfl_xor(vmn, 16, 64)); vmn = fminf(vmn, __shfl_xor(vmn, 32, 64));
    float vsq = s_sq[s];
    vsq += __shfl_xor(vsq, 16, 64); vsq += __shfl_xor(vsq, 32, 64);
    float vav = s_av[s];
    vav += __shfl_xor(vav, 16, 64); vav += __shfl_xor(vav, 32, 64);
    float vss = s_ss[s];
    vss += __shfl_xor(vss, 16, 64); vss += __shfl_xor(vss, 32, 64);
    if (lane < 16) {
      int e = wave * 16 + lane;
      size_t base = ((size_t)s * B_ + b) * K6_;
      float meanv = vmean / nvf;
      float stdv = sqrtf(fmaxf(vsq / nvf - meanv * meanv, 1e-6f));
      float mnv = fminf(fmaxf(vmn, -1e4f), 1e4f);
      feats[base + e] = f2bf(meanv);
      feats[base + 256 + e] = f2bf(vmx);
      feats[base + 512 + e] = f2bf(mnv);
      feats[base + 768 + e] = f2bf(stdv);
      feats[base + 1024 + e] = f2bf(vav / vss);
    }
  }
}

// ------- K2: h = feats(bf16) @ sp_w^T + bias -> hbuf (pre-LN, fp32) -------
// grid 768: (3 s) x (64 b-tiles of 16) x (4 e-quarters of 64). 3 blocks/CU.
__global__ __launch_bounds__(256) void k2_kernel(
    const unsigned short* __restrict__ feats, const unsigned short* __restrict__ spw_bf,
    const float* __restrict__ sp_b, float* __restrict__ hbuf) {
  __shared__ __align__(16) unsigned int a[16 * 132];
  int id = blockIdx.x;
  int s = id >> 8;
  int rem = id & 255;
  int b0 = (rem >> 2) * 16;
  int e0 = (rem & 3) * 64;
  int tid = threadIdx.x, lane = tid & 63, wave = tid >> 6;
  int row16 = lane & 15, quad = lane >> 4;
  int e = e0 + wave * 16 + row16;
  f32x4 acc;
#pragma unroll
  for (int cc = 0; cc < 4; ++cc) acc[cc] = 0.f;

  for (int kc = 0; kc < 6; ++kc) {
    __syncthreads();
    for (int j = tid; j < 512; j += 256) {
      int rw = j >> 5, ck = j & 31;
      bf16x8 v = *(const bf16x8*)(feats + ((size_t)s * B_ + b0 + rw) * K6_ + kc * 256 + ck * 8);
      *(bf16x8*)((unsigned short*)&a[rw * 132] + ck * 8) = v;
    }
    __syncthreads();
#pragma unroll
    for (int ks = 0; ks < 8; ++ks) {
      bf16x8 af = *(const bf16x8*)&a[row16 * 132 + ks * 16 + quad * 4];
      bf16x8 bfr = *(const bf16x8*)(spw_bf + ((size_t)s * E_ + e) * K6_ + kc * 256 + ks * 32 + quad * 8);
      acc = __builtin_amdgcn_mfma_f32_16x16x32_bf16(af, bfr, acc, 0, 0, 0);
    }
  }
  {
    float bias = sp_b[s * 256 + e];
#pragma unroll
    for (int rg = 0; rg < 4; ++rg) {
      int rw = quad * 4 + rg;
      hbuf[((size_t)s * B_ + b0 + rw) * 256 + e] = acc[rg] + bias;
    }
  }
}

// ------- K3: per b: for each s LN+gelu, weighted sum, final LN -> out -------
__global__ __launch_bounds__(256) void k3_kernel(
    const float* __restrict__ hbuf, const float* __restrict__ wts,
    const float* __restrict__ ln_g, const float* __restrict__ ln_b,
    const float* __restrict__ on_g, const float* __restrict__ on_b,
    float* __restrict__ out) {
  __shared__ float rs[4], rq[4];
  int b = blockIdx.x, tid = threadIdx.x, lane = tid & 63, wave = tid >> 6;
  float o = 0.f;
#pragma unroll
  for (int s = 0; s < 3; ++s) {
    float h = hbuf[((size_t)s * B_ + b) * 256 + tid];
    float sum = h, sq = h * h;
#pragma unroll
    for (int off = 32; off >= 1; off >>= 1) {
      sum += __shfl_xor(sum, off, 64);
      sq += __shfl_xor(sq, off, 64);
    }
    if (lane == 0) { rs[wave] = sum; rq[wave] = sq; }
    __syncthreads();
    float ts = rs[0] + rs[1] + rs[2] + rs[3];
    float tq = rq[0] + rq[1] + rq[2] + rq[3];
    __syncthreads();
    float mu = ts * (1.f / 256.f);
    float var = tq * (1.f / 256.f) - mu * mu;
    float rstd = rsqrtf(var + 1e-5f);
    float v = (h - mu) * rstd * ln_g[s * 256 + tid] + ln_b[s * 256 + tid];
    o += wts[b * 4 + s] * gelu_exact(v);
  }
  float sum = o, sq = o * o;
#pragma unroll
  for (int off = 32; off >= 1; off >>= 1) {
    sum += __shfl_xor(sum, off, 64);
    sq += __shfl_xor(sq, off, 64);
  }
  if (lane == 0) { rs[wave] = sum; rq[wave] = sq; }
  __syncthreads();
  float ts = rs[0] + rs[1] + rs[2] + rs[3];
  float tq = rq[0] + rq[1] + rq[2] + rq[3];
  float mu = ts * (1.f / 256.f);
  float var = tq * (1.f / 256.f) - mu * mu;
  float rstd = rsqrtf(var + 1e-5f);
  out[(size_t)b * 256 + tid] = (o - mu) * rstd * on_g[tid] + on_b[tid];
}

extern "C" void kernel_launch(void* const* d_in, const int* in_sizes, int n_in,
                              void* d_out, int out_size, void* d_ws, size_t ws_size,
                              hipStream_t stream) {
  const float* e_emb   = (const float*)d_in[0];
  const float* nb_rel  = (const float*)d_in[1];
  const float* delta_t = (const float*)d_in[2];
  const float* r_emb   = (const float*)d_in[3];
  const unsigned char* hist_mask = (const unsigned char*)d_in[4]; // dtype auto-detected
  const float* rel_w   = (const float*)d_in[5];
  const float* lt1     = (const float*)d_in[6];
  const float* lt2     = (const float*)d_in[7];
  const float* shp     = (const float*)d_in[8];
  const float* lgm     = (const float*)d_in[9];
  const float* attn_w  = (const float*)d_in[10];
  const float* sp_w    = (const float*)d_in[11];
  const float* sp_b    = (const float*)d_in[12];
  const float* ln_g    = (const float*)d_in[13];
  const float* ln_b    = (const float*)d_in[14];
  const float* csq_w   = (const float*)d_in[15];
  const float* csq_b   = (const float*)d_in[16];
  const float* csl_w   = (const float*)d_in[17];
  const float* csl_b   = (const float*)d_in[18];
  const float* on_g    = (const float*)d_in[19];
  const float* on_b    = (const float*)d_in[20];
  float* out = (float*)d_out;

  char* ws = (char*)d_ws;
  unsigned short* rw_bf  = (unsigned short*)(ws + 0);         // 131072 B
  unsigned short* spw_bf = (unsigned short*)(ws + 131072);    // 2359296 B
  unsigned short* t_bf   = (unsigned short*)(ws + 2490368);   // 1572864 B
  float* wts    = (float*)(ws + 4063232);                     // 16 KB
  unsigned short* feats = (unsigned short*)(ws + 4079616);    // 9437184 B
  float* hbuf   = (float*)(ws + 13516800);                    // 3 MB (total ~16.7 MB)

  hipLaunchKernelGGL(k_cast, dim3(4864), dim3(256), 0, stream, rel_w, sp_w, rw_bf, spw_bf);
  hipLaunchKernelGGL(k_prep, dim3(256), dim3(256), 0, stream, r_emb, rel_w, csq_w, csq_b,
                     csl_w, csl_b, attn_w, t_bf, wts);
  hipLaunchKernelGGL(k1_main, dim3(1024), dim3(1024), 0, stream, nb_rel, delta_t, hist_mask,
                     e_emb, lt1, lt2, shp, lgm, rw_bf, t_bf, feats);
  hipLaunchKernelGGL(k2_kernel, dim3(768), dim3(256), 0, stream, feats, spw_bf, sp_b, hbuf);
  hipLaunchKernelGGL(k3_kernel, dim3(1024), dim3(256), 0, stream, hbuf, wts, ln_g, ln_b,
                     on_g, on_b, out);
}

// Round 6
// 484.209 us; speedup vs baseline: 1.3934x; 1.3934x over previous
//
#include <hip/hip_runtime.h>
#include <hip/hip_bf16.h>
#include <math.h>

#define B_   1024
#define N_   200
#define NR_  208      // padded rows (13 x 16)
#define NT_  13
#define E_   256
#define R_   256
#define K6_  1536

typedef __attribute__((ext_vector_type(8))) short bf16x8;
typedef __attribute__((ext_vector_type(4))) float f32x4;

__device__ __forceinline__ unsigned short f2bf(float f) {
  unsigned int u = __float_as_uint(f);
  u += 0x7fffu + ((u >> 16) & 1u);          // RNE
  return (unsigned short)(u >> 16);
}

// HW packed cvt (v_cvt_pk_bf16_f32), RNE — bit-identical to f2bf for finite vals
__device__ __forceinline__ unsigned int pk_bf(float lo, float hi) {
  float2 t; t.x = lo; t.y = hi;
  __hip_bfloat162 h = __float22bfloat162_rn(t);
  unsigned int u;
  __builtin_memcpy(&u, &h, 4);
  return u;
}

__device__ __forceinline__ float gelu_exact(float x) {
  return 0.5f * x * (1.f + erff(x * 0.70710678118654752f));
}

// ---- k_cast: build bf16 fragment layouts + fp32 transposes in ws ----
// rwf : rel_w bf16, MFMA-B fragment order [et][ks][quad][row16][8]
// spwf: sp_w  bf16, fragment order [s][et][kc][ks][quad][row16][8]
// rwT : rel_w^T fp32 [r][e];  cwT: csq_w^T fp32 [r][e];  awT: attn_w^T fp32 [s][e'][e]
__global__ __launch_bounds__(256) void k_cast(
    const float* __restrict__ rel_w, const float* __restrict__ sp_w,
    const float* __restrict__ csq_w, const float* __restrict__ attn_w,
    unsigned short* __restrict__ rwf, unsigned short* __restrict__ spwf,
    float* __restrict__ rwT, float* __restrict__ cwT, float* __restrict__ awT) {
  int o = blockIdx.x * 256 + threadIdx.x;
  // rwf: 65536
  if (o < 65536) {
    int j = o & 7, r16 = (o >> 3) & 15, quad = (o >> 7) & 3, ks = (o >> 9) & 7, et = o >> 12;
    rwf[o] = f2bf(rel_w[(size_t)(et * 16 + r16) * 256 + ks * 32 + quad * 8 + j]);
    return;
  }
  o -= 65536;
  // spwf: 1179648
  if (o < 1179648) {
    int j = o & 7, r16 = (o >> 3) & 15, quad = (o >> 7) & 3, ks = (o >> 9) & 7;
    int rest = o >> 12;                 // = ((s*16+et)*6 + kc)
    int kc = rest % 6, se = rest / 6;
    int et = se & 15, s = se >> 4;
    spwf[o] = f2bf(sp_w[(size_t)(s * 256 + et * 16 + r16) * 1536 + kc * 256 + ks * 32 + quad * 8 + j]);
    return;
  }
  o -= 1179648;
  if (o < 65536) { int r = o >> 8, e = o & 255; rwT[o] = rel_w[(size_t)e * 256 + r]; return; }
  o -= 65536;
  if (o < 65536) { int r = o >> 8, e = o & 255; cwT[o] = csq_w[(size_t)e * 256 + r]; return; }
  o -= 65536;
  if (o < 196608) {
    int s = o >> 16, rem = o & 65535, ep = rem >> 8, e = rem & 255;
    awT[o] = attn_w[((size_t)s * 256 + e) * 256 + ep];
  }
}

// ------- k_prep: fp32, fully coalesced via transposed weights -------
// qk/sqs -> csl logits/wts -> qp -> t(bf16). Accumulation order = original.
__global__ __launch_bounds__(256) void k_prep(
    const float* __restrict__ r_emb, const float* __restrict__ rwT,
    const float* __restrict__ cwT, const float* __restrict__ awT,
    const float* __restrict__ csq_b, const float* __restrict__ csl_w,
    const float* __restrict__ csl_b, const float* __restrict__ rel_w,
    unsigned short* __restrict__ t_bf, float* __restrict__ wts) {
  __shared__ __align__(16) float re[4][256];
  __shared__ __align__(16) float qk[4][256];
  __shared__ __align__(16) float sqs[4][256];
  __shared__ __align__(16) float qp[3][4][256];
  __shared__ float lg[4][3];
  int b0 = blockIdx.x * 4;
  int tid = threadIdx.x;
  int e = tid;
#pragma unroll
  for (int i = 0; i < 4; ++i)
    re[i][tid] = r_emb[(size_t)(b0 + i) * 256 + tid];
  __syncthreads();
  // ---- qk + sqs: lane = e, iterate r; rwT/cwT loads coalesced (256B/wave) ----
  {
    float qkv[4], sv[4];
#pragma unroll
    for (int i = 0; i < 4; ++i) { qkv[i] = 0.f; sv[i] = 0.f; }
    for (int g = 0; g < 64; ++g) {
      float4 xi[4];
#pragma unroll
      for (int i = 0; i < 4; ++i) xi[i] = ((const float4*)re[i])[g];  // LDS broadcast
#pragma unroll
      for (int k = 0; k < 4; ++k) {
        int r = g * 4 + k;
        float w = rwT[(size_t)r * 256 + e];
        float c = cwT[(size_t)r * 256 + e];
#pragma unroll
        for (int i = 0; i < 4; ++i) {
          float x = (k == 0) ? xi[i].x : (k == 1) ? xi[i].y : (k == 2) ? xi[i].z : xi[i].w;
          qkv[i] = fmaf(w, x, qkv[i]);
          sv[i]  = fmaf(c, x, sv[i]);
        }
      }
    }
    float cb = csq_b[e];
#pragma unroll
    for (int i = 0; i < 4; ++i) {
      qk[i][e] = qkv[i];
      sqs[i][e] = sv[i] + cb;
    }
  }
  __syncthreads();
  if (tid < 12) {
    int i = tid / 3, k = tid % 3;
    float acc = csl_b[k];
    for (int ee = 0; ee < 256; ++ee) acc += sqs[i][ee] * csl_w[k * 256 + ee];
    lg[i][k] = acc;
  }
  __syncthreads();
  if (tid < 4) {
    float l0 = lg[tid][0], l1 = lg[tid][1], l2 = lg[tid][2];
    float m = fmaxf(l0, fmaxf(l1, l2));
    float e0 = expf(l0 - m), e1 = expf(l1 - m), e2 = expf(l2 - m);
    float inv = 1.f / (e0 + e1 + e2);
    wts[(b0 + tid) * 4 + 0] = e0 * inv;
    wts[(b0 + tid) * 4 + 1] = e1 * inv;
    wts[(b0 + tid) * 4 + 2] = e2 * inv;
  }
  // ---- qp: lane = e, iterate e'; awT loads coalesced ----
  {
    float qpv[3][4];
#pragma unroll
    for (int s = 0; s < 3; ++s)
#pragma unroll
      for (int i = 0; i < 4; ++i) qpv[s][i] = 0.f;
    for (int g = 0; g < 64; ++g) {
      float4 qf[4];
#pragma unroll
      for (int i = 0; i < 4; ++i) qf[i] = ((const float4*)qk[i])[g];  // LDS broadcast
#pragma unroll
      for (int k = 0; k < 4; ++k) {
        int ep = g * 4 + k;
#pragma unroll
        for (int s = 0; s < 3; ++s) {
          float w = awT[((size_t)s * 256 + ep) * 256 + e];
#pragma unroll
          for (int i = 0; i < 4; ++i) {
            float x = (k == 0) ? qf[i].x : (k == 1) ? qf[i].y : (k == 2) ? qf[i].z : qf[i].w;
            qpv[s][i] = fmaf(w, x, qpv[s][i]);
          }
        }
      }
    }
    __syncthreads();
#pragma unroll
    for (int s = 0; s < 3; ++s)
#pragma unroll
      for (int i = 0; i < 4; ++i) qp[s][i][e] = qpv[s][i];
  }
  __syncthreads();
  // ---- t: lane = r, iterate e; rel_w loads coalesced (original pattern) ----
  {
    int r = tid;
    float tacc[3][4];
#pragma unroll
    for (int s = 0; s < 3; ++s)
#pragma unroll
      for (int i = 0; i < 4; ++i) tacc[s][i] = 0.f;
    for (int e4 = 0; e4 < 64; ++e4) {
      float4 qv[3][4];
#pragma unroll
      for (int s = 0; s < 3; ++s)
#pragma unroll
        for (int i = 0; i < 4; ++i)
          qv[s][i] = ((const float4*)qp[s][i])[e4];
#pragma unroll
      for (int j = 0; j < 4; ++j) {
        float w = rel_w[(size_t)(e4 * 4 + j) * 256 + r];
#pragma unroll
        for (int s = 0; s < 3; ++s)
#pragma unroll
          for (int i = 0; i < 4; ++i) {
            float q = (j == 0) ? qv[s][i].x : (j == 1) ? qv[s][i].y
                      : (j == 2) ? qv[s][i].z : qv[s][i].w;
            tacc[s][i] = fmaf(q, w, tacc[s][i]);
          }
      }
    }
#pragma unroll
    for (int s = 0; s < 3; ++s)
#pragma unroll
      for (int i = 0; i < 4; ++i)
        t_bf[((size_t)(b0 + i) * 3 + s) * 256 + r] = f2bf(tacc[s][i]);
  }
}

// ------------- K1: Round-1 structure (measured 170 us) -------------
// Full 208x256 bf16 tile in LDS, burst staging (MLP=13), per-wave MFMA logits,
// 3-wave softmax, single stats GEMM. Micro-bits: t_bf bf16 fragments, pk_bf
// packing, rwf fragment-order bfr loads (coalesced).
__global__ __launch_bounds__(1024, 4) void k1_main(
    const float* __restrict__ nb_rel, const float* __restrict__ delta_t,
    const unsigned char* __restrict__ hm_raw, const float* __restrict__ e_emb,
    const float* __restrict__ p_lt1, const float* __restrict__ p_lt2,
    const float* __restrict__ p_sh, const float* __restrict__ p_lgm,
    const unsigned short* __restrict__ rwf, const unsigned short* __restrict__ t_bf,
    unsigned short* __restrict__ feats) {
  __shared__ __align__(16) struct {
    unsigned int a[NR_ * 132];   // bf16 tile, row stride 264 bf16 (256 data + 8 pad)
    float c[3][NR_];             // unmasked per-scale decay*window weights
    float p[3][NR_];             // logits -> exp scratch
    float nmeta[NR_ * 12];       // [0..2]=mf*c [3]=off(0|1e4) [4..6]=q [7]=mf
  } sm;
  int b = blockIdx.x;
  int tid = threadIdx.x;
  int lane = tid & 63, wave = tid >> 6;
  int row16 = lane & 15, quad = lane >> 4;

  // ---- mask dtype detection: probe first 1024 bytes ----
  int hasNZoff = 0, hasFP = 0;
  {
    unsigned char cc = hm_raw[tid];
    if ((tid & 3) != 0 && cc != 0) {
      hasNZoff = 1;
      if (cc == 0x3Fu || cc == 0x80u) hasFP = 1;
    }
  }
  int cntNZ = __syncthreads_count(hasNZoff);
  int cntFP = __syncthreads_count(hasFP);
  int mmode = (cntNZ == 0) ? 0 : (cntFP > 0 ? 2 : 1);  // 0=int32 1=bool 2=f32

  float tau1 = __expf(p_lt1[0]);
  float tau2 = __expf(p_lt2[0]) + tau1;
  float sharp = fminf(fmaxf(p_sh[0], 0.1f), 5.0f);
  float gamma = __expf(p_lgm[0]);

  bool mk = false;
  if (tid < NR_) {
    float mf = 0.f, c0 = 0.f, c1 = 0.f, c2 = 0.f;
    if (tid < N_) {
      size_t mi = (size_t)b * N_ + tid;
      if (mmode == 0)      mk = ((const int*)hm_raw)[mi] != 0;
      else if (mmode == 1) mk = hm_raw[mi] != 0;
      else                 mk = ((const float*)hm_raw)[mi] != 0.f;
      float dt = delta_t[mi];
      mf = mk ? 1.f : 0.f;
      float decay = __expf(-gamma * fmaxf(dt, 0.f));
      float wf = 1.f / (1.f + __expf(sharp * (dt - tau1)));
      float wc = 1.f / (1.f + __expf(-sharp * (dt - tau2)));
      float wm = fmaxf(1.f - wf - wc, 0.f);
      c0 = decay * wf; c1 = decay * wm; c2 = decay * wc;
    }
    sm.c[0][tid] = c0; sm.c[1][tid] = c1; sm.c[2][tid] = c2;
    f32x4 w0, w1;
    w0[0] = mf * c0; w0[1] = mf * c1; w0[2] = mf * c2; w0[3] = mk ? 0.f : 1e4f;
    w1[0] = 0.f; w1[1] = 0.f; w1[2] = 0.f; w1[3] = mf;
    *(f32x4*)&sm.nmeta[tid * 12]     = w0;
    *(f32x4*)&sm.nmeta[tid * 12 + 4] = w1;
  }
  int cnt = __syncthreads_count(mk ? 1 : 0);
  float nvf = fmaxf((float)cnt, 1.f);
  bool allinv = (cnt == 0);

  // ---- burst staging: issue all 13 loads (MLP=13), then pack to LDS ----
  {
    const float* src = nb_rel + (size_t)b * N_ * 256;
    float4 xs[NT_];
#pragma unroll
    for (int i = 0; i < NT_; ++i) {
      int n = i * 16 + wave;
      int gn = (n < N_) ? n : (N_ - 1);
      xs[i] = *(const float4*)(src + (size_t)gn * 256 + lane * 4);
    }
#pragma unroll
    for (int i = 0; i < NT_; ++i) {
      uint2 pk;
      pk.x = pk_bf(xs[i].x, xs[i].y);
      pk.y = pk_bf(xs[i].z, xs[i].w);
      *(uint2*)&sm.a[(i * 16 + wave) * 132 + lane * 2] = pk;
    }
  }
  __syncthreads();

  // ---- logit dots via MFMA: wave nt computes araw for its 16 rows, 3 scales.
  if (wave < NT_) {
    bf16x8 tfrag[8];
    {
      int sr = (row16 < 3) ? row16 : 0;
      const unsigned short* tb = t_bf + ((size_t)b * 3 + sr) * 256 + quad * 8;
      bf16x8 zer = {0, 0, 0, 0, 0, 0, 0, 0};
#pragma unroll
      for (int ks = 0; ks < 8; ++ks) {
        bf16x8 tv = *(const bf16x8*)(tb + ks * 32);
        tfrag[ks] = (row16 < 3) ? tv : zer;
      }
    }
    f32x4 acc;
#pragma unroll
    for (int cc = 0; cc < 4; ++cc) acc[cc] = 0.f;
#pragma unroll
    for (int ks = 0; ks < 8; ++ks) {
      bf16x8 af = *(const bf16x8*)&sm.a[(wave * 16 + row16) * 132 + ks * 16 + quad * 4];
      acc = __builtin_amdgcn_mfma_f32_16x16x32_bf16(af, tfrag[ks], acc, 0, 0, 0);
    }
    if (row16 < 3) {
#pragma unroll
      for (int rg = 0; rg < 4; ++rg) {
        int n = wave * 16 + quad * 4 + rg;      // C layout: col=lane&15, row=quad*4+rg
        float cw = sm.c[row16][n];
        float mf = sm.nmeta[n * 12 + 7];
        float l = cw * acc[rg] * 0.0625f;
        l = (mf > 0.5f) ? l : -1e4f;
        if (allinv) l = (n < N_) ? 0.f : -1e4f;
        sm.p[row16][n] = l;
      }
    }
  } else if (wave == NT_) {
    // e_emb tail copy overlapped with the dot phase
    for (int i = lane; i < 256; i += 64) {
      unsigned short v = f2bf(e_emb[(size_t)b * 256 + i]);
      feats[((size_t)0 * B_ + b) * K6_ + 1280 + i] = v;
      feats[((size_t)1 * B_ + b) * K6_ + 1280 + i] = v;
      feats[((size_t)2 * B_ + b) * K6_ + 1280 + i] = v;
    }
  }

  // B-fragment preload (wave owns 16 e-cols) — fragment-order rwf, coalesced
  bf16x8 bfr[8];
  {
#pragma unroll
    for (int ks = 0; ks < 8; ++ks)
      bfr[ks] = *(const bf16x8*)(rwf + ((((size_t)wave * 8 + ks) * 4 + quad) * 16 + row16) * 8);
  }
  __syncthreads();

  // ---- softmax (waves 0-2): max -> exp(store back) -> normalize into q ----
  if (wave < 3) {
    int s = wave;
    float m = -1e30f;
    for (int n = lane; n < NR_; n += 64) m = fmaxf(m, sm.p[s][n]);
#pragma unroll
    for (int o = 32; o >= 1; o >>= 1) m = fmaxf(m, __shfl_xor(m, o, 64));
    float ssum = 0.f;
    for (int n = lane; n < NR_; n += 64) {
      float ev = __expf(sm.p[s][n] - m);
      sm.p[s][n] = ev;
      ssum += ev;
    }
#pragma unroll
    for (int o = 32; o >= 1; o >>= 1) ssum += __shfl_xor(ssum, o, 64);
    float inv = 1.f / ssum;
    for (int n = lane; n < NR_; n += 64)
      sm.nmeta[n * 12 + 4 + s] = sm.p[s][n] * inv * sm.c[s][n];
  }
  __syncthreads();

  // ---- MFMA GEMM over 13 n-tiles + register stats (wave owns 16 e-cols) ----
  float s_mean[3], s_mx[3], s_mn[3], s_sq[3], s_av[3];
#pragma unroll
  for (int s = 0; s < 3; ++s) {
    s_mean[s] = 0.f; s_mx[s] = -1e30f; s_mn[s] = 1e30f;
    s_sq[s] = 0.f; s_av[s] = 0.f;
  }

  for (int nt = 0; nt < NT_; ++nt) {
    f32x4 acc;
#pragma unroll
    for (int cc = 0; cc < 4; ++cc) acc[cc] = 0.f;
#pragma unroll
    for (int ks = 0; ks < 8; ++ks) {
      bf16x8 af = *(const bf16x8*)&sm.a[(nt * 16 + row16) * 132 + ks * 16 + quad * 4];
      acc = __builtin_amdgcn_mfma_f32_16x16x32_bf16(af, bfr[ks], acc, 0, 0, 0);
    }
    int nb = nt * 16 + quad * 4;
#pragma unroll
    for (int rg = 0; rg < 4; ++rg) {
      const float* nm = &sm.nmeta[(size_t)(nb + rg) * 12];
      f32x4 w0 = *(const f32x4*)nm;        // cm0 cm1 cm2 off   (broadcast b128)
      f32x4 w1 = *(const f32x4*)(nm + 4);  // q0  q1  q2  mf    (broadcast b128)
      float m = acc[rg];
#pragma unroll
      for (int s = 0; s < 3; ++s) {
        float vm = w0[s] * m;
        s_mean[s] += vm;
        s_mx[s] = fmaxf(s_mx[s], vm);
        s_mn[s] = fminf(s_mn[s], fmaf(w0[s], m, w0[3]));
        float cv = fminf(fmaxf(vm, -10.f), 10.f);
        s_sq[s] = fmaf(cv, cv, s_sq[s]);
        s_av[s] = fmaf(w1[s], m, s_av[s]);
      }
    }
  }

  // ---- reduce across quads, write feats (bf16) ----
#pragma unroll
  for (int s = 0; s < 3; ++s) {
    float vmean = s_mean[s];
    vmean += __shfl_xor(vmean, 16, 64); vmean += __shfl_xor(vmean, 32, 64);
    float vmx = s_mx[s];
    vmx = fmaxf(vmx, __shfl_xor(vmx, 16, 64)); vmx = fmaxf(vmx, __shfl_xor(vmx, 32, 64));
    float vmn = s_mn[s];
    vmn = fminf(vmn, __shfl_xor(vmn, 16, 64)); vmn = fminf(vmn, __shfl_xor(vmn, 32, 64));
    float vsq = s_sq[s];
    vsq += __shfl_xor(vsq, 16, 64); vsq += __shfl_xor(vsq, 32, 64);
    float vav = s_av[s];
    vav += __shfl_xor(vav, 16, 64); vav += __shfl_xor(vav, 32, 64);
    if (lane < 16) {
      int e = wave * 16 + lane;
      size_t base = ((size_t)s * B_ + b) * K6_;
      float meanv = vmean / nvf;
      float stdv = sqrtf(fmaxf(vsq / nvf - meanv * meanv, 1e-6f));
      float mnv = fminf(fmaxf(vmn, -1e4f), 1e4f);
      feats[base + e] = f2bf(meanv);
      feats[base + 256 + e] = f2bf(vmx);
      feats[base + 512 + e] = f2bf(mnv);
      feats[base + 768 + e] = f2bf(stdv);
      feats[base + 1024 + e] = f2bf(vav);
    }
  }
}

// ------- K2: h = feats(bf16) @ sp_w^T + bias -> hbuf (single-stage) -------
// grid 768: (3 s) x (64 b-tiles of 16) x (4 e-quarters of 64). Whole A-panel
// staged once (burst, 1 barrier), 48 MFMAs with fragment-order coalesced B.
// A row stride 1544 shorts (1536 + 8 pad): 3088 B = 16B-aligned for b128, and
// 772 uints ≡ 4 (mod 32) -> fragment reads hit 8 disjoint 4-bank spans with
// 8 lanes each = the 8-cycle wave64 b128 minimum (bank-optimal).
__global__ __launch_bounds__(256) void k2_kernel(
    const unsigned short* __restrict__ feats, const unsigned short* __restrict__ spwf,
    const float* __restrict__ sp_b, float* __restrict__ hbuf) {
  __shared__ __align__(16) unsigned short A[16][1544];
  int id = blockIdx.x;
  int s = id >> 8;
  int rem = id & 255;
  int b0 = (rem >> 2) * 16;
  int e0 = (rem & 3) * 64;
  int tid = threadIdx.x, lane = tid & 63, wave = tid >> 6;
  int row16 = lane & 15, quad = lane >> 4;

  // burst-stage A: 3072 bf16x8 chunks, 12 per thread
  bf16x8 v[12];
#pragma unroll
  for (int t = 0; t < 12; ++t) {
    int j = tid + t * 256;
    int rw = j / 192, ck = j % 192;
    v[t] = *(const bf16x8*)(feats + ((size_t)s * B_ + b0 + rw) * K6_ + ck * 8);
  }
#pragma unroll
  for (int t = 0; t < 12; ++t) {
    int j = tid + t * 256;
    int rw = j / 192, ck = j % 192;
    *(bf16x8*)&A[rw][ck * 8] = v[t];
  }
  __syncthreads();

  int et = (e0 >> 4) + wave;
  const unsigned short* bp = spwf + (((size_t)s * 16 + et) * 6) * 4096;  // *8ks*4q*16r*8j
  f32x4 acc;
#pragma unroll
  for (int cc = 0; cc < 4; ++cc) acc[cc] = 0.f;
#pragma unroll
  for (int kc = 0; kc < 6; ++kc) {
#pragma unroll
    for (int ks = 0; ks < 8; ++ks) {
      bf16x8 af = *(const bf16x8*)&A[row16][kc * 256 + ks * 32 + quad * 8];
      bf16x8 bf = *(const bf16x8*)(bp + ((size_t)(kc * 8 + ks) * 4 + quad) * 128 + row16 * 8);
      acc = __builtin_amdgcn_mfma_f32_16x16x32_bf16(af, bf, acc, 0, 0, 0);
    }
  }
  {
    int e = e0 + wave * 16 + row16;
    float bias = sp_b[s * 256 + e];
#pragma unroll
    for (int rg = 0; rg < 4; ++rg) {
      int rw = quad * 4 + rg;
      hbuf[((size_t)s * B_ + b0 + rw) * 256 + e] = acc[rg] + bias;
    }
  }
}

// ------- K3: per b: for each s LN+gelu, weighted sum, final LN -> out -------
__global__ __launch_bounds__(256) void k3_kernel(
    const float* __restrict__ hbuf, const float* __restrict__ wts,
    const float* __restrict__ ln_g, const float* __restrict__ ln_b,
    const float* __restrict__ on_g, const float* __restrict__ on_b,
    float* __restrict__ out) {
  __shared__ float rs[4], rq[4];
  int b = blockIdx.x, tid = threadIdx.x, lane = tid & 63, wave = tid >> 6;
  float o = 0.f;
#pragma unroll
  for (int s = 0; s < 3; ++s) {
    float h = hbuf[((size_t)s * B_ + b) * 256 + tid];
    float sum = h, sq = h * h;
#pragma unroll
    for (int off = 32; off >= 1; off >>= 1) {
      sum += __shfl_xor(sum, off, 64);
      sq += __shfl_xor(sq, off, 64);
    }
    if (lane == 0) { rs[wave] = sum; rq[wave] = sq; }
    __syncthreads();
    float ts = rs[0] + rs[1] + rs[2] + rs[3];
    float tq = rq[0] + rq[1] + rq[2] + rq[3];
    __syncthreads();
    float mu = ts * (1.f / 256.f);
    float var = tq * (1.f / 256.f) - mu * mu;
    float rstd = rsqrtf(var + 1e-5f);
    float v = (h - mu) * rstd * ln_g[s * 256 + tid] + ln_b[s * 256 + tid];
    o += wts[b * 4 + s] * gelu_exact(v);
  }
  float sum = o, sq = o * o;
#pragma unroll
  for (int off = 32; off >= 1; off >>= 1) {
    sum += __shfl_xor(sum, off, 64);
    sq += __shfl_xor(sq, off, 64);
  }
  if (lane == 0) { rs[wave] = sum; rq[wave] = sq; }
  __syncthreads();
  float ts = rs[0] + rs[1] + rs[2] + rs[3];
  float tq = rq[0] + rq[1] + rq[2] + rq[3];
  float mu = ts * (1.f / 256.f);
  float var = tq * (1.f / 256.f) - mu * mu;
  float rstd = rsqrtf(var + 1e-5f);
  out[(size_t)b * 256 + tid] = (o - mu) * rstd * on_g[tid] + on_b[tid];
}

extern "C" void kernel_launch(void* const* d_in, const int* in_sizes, int n_in,
                              void* d_out, int out_size, void* d_ws, size_t ws_size,
                              hipStream_t stream) {
  const float* e_emb   = (const float*)d_in[0];
  const float* nb_rel  = (const float*)d_in[1];
  const float* delta_t = (const float*)d_in[2];
  const float* r_emb   = (const float*)d_in[3];
  const unsigned char* hist_mask = (const unsigned char*)d_in[4]; // dtype auto-detected
  const float* rel_w   = (const float*)d_in[5];
  const float* lt1     = (const float*)d_in[6];
  const float* lt2     = (const float*)d_in[7];
  const float* shp     = (const float*)d_in[8];
  const float* lgm     = (const float*)d_in[9];
  const float* attn_w  = (const float*)d_in[10];
  const float* sp_w    = (const float*)d_in[11];
  const float* sp_b    = (const float*)d_in[12];
  const float* ln_g    = (const float*)d_in[13];
  const float* ln_b    = (const float*)d_in[14];
  const float* csq_w   = (const float*)d_in[15];
  const float* csq_b   = (const float*)d_in[16];
  const float* csl_w   = (const float*)d_in[17];
  const float* csl_b   = (const float*)d_in[18];
  const float* on_g    = (const float*)d_in[19];
  const float* on_b    = (const float*)d_in[20];
  float* out = (float*)d_out;

  char* ws = (char*)d_ws;
  unsigned short* rwf   = (unsigned short*)(ws + 0);          // 131072 B (fragment order)
  unsigned short* spwf  = (unsigned short*)(ws + 131072);     // 2359296 B (fragment order)
  unsigned short* t_bf  = (unsigned short*)(ws + 2490368);    // 1572864 B
  float* wts    = (float*)(ws + 4063232);                     // 16 KB
  unsigned short* feats = (unsigned short*)(ws + 4079616);    // 9437184 B
  float* hbuf   = (float*)(ws + 13516800);                    // 3145728 B
  float* rwT    = (float*)(ws + 16662528);                    // 262144 B
  float* cwT    = (float*)(ws + 16924672);                    // 262144 B
  float* awT    = (float*)(ws + 17186816);                    // 786432 B (total ~18.0 MB)

  hipLaunchKernelGGL(k_cast, dim3(6144), dim3(256), 0, stream, rel_w, sp_w, csq_w, attn_w,
                     rwf, spwf, rwT, cwT, awT);
  hipLaunchKernelGGL(k_prep, dim3(256), dim3(256), 0, stream, r_emb, rwT, cwT, awT,
                     csq_b, csl_w, csl_b, rel_w, t_bf, wts);
  hipLaunchKernelGGL(k1_main, dim3(1024), dim3(1024), 0, stream, nb_rel, delta_t, hist_mask,
                     e_emb, lt1, lt2, shp, lgm, rwf, t_bf, feats);
  hipLaunchKernelGGL(k2_kernel, dim3(768), dim3(256), 0, stream, feats, spwf, sp_b, hbuf);
  hipLaunchKernelGGL(k3_kernel, dim3(1024), dim3(256), 0, stream, hbuf, wts, ln_g, ln_b,
                     on_g, on_b, out);
}

// Round 7
// 473.997 us; speedup vs baseline: 1.4235x; 1.0215x over previous
//
#include <hip/hip_runtime.h>
#include <hip/hip_bf16.h>
#include <math.h>

#define B_   1024
#define N_   200
#define NR_  208      // padded rows (13 x 16)
#define NT_  13
#define E_   256
#define R_   256
#define K6_  1536

typedef __attribute__((ext_vector_type(8))) short bf16x8;
typedef __attribute__((ext_vector_type(4))) float f32x4;

__device__ __forceinline__ unsigned short f2bf(float f) {
  unsigned int u = __float_as_uint(f);
  u += 0x7fffu + ((u >> 16) & 1u);          // RNE
  return (unsigned short)(u >> 16);
}

// HW packed cvt (v_cvt_pk_bf16_f32), RNE — bit-identical to f2bf for finite vals
__device__ __forceinline__ unsigned int pk_bf(float lo, float hi) {
  float2 t; t.x = lo; t.y = hi;
  __hip_bfloat162 h = __float22bfloat162_rn(t);
  unsigned int u;
  __builtin_memcpy(&u, &h, 4);
  return u;
}

__device__ __forceinline__ float gelu_exact(float x) {
  return 0.5f * x * (1.f + erff(x * 0.70710678118654752f));
}

// ---- k_cast: build bf16 fragment layouts + fp32 transposes in ws ----
// rwf : rel_w bf16, MFMA-B fragment order [et][ks][quad][row16][8]
// spwf: sp_w  bf16, fragment order [s][et][kc][ks][quad][row16][8]
// rwT : rel_w^T fp32 [r][e];  cwT: csq_w^T fp32 [r][e];  awT: attn_w^T fp32 [s][e'][e]
__global__ __launch_bounds__(256) void k_cast(
    const float* __restrict__ rel_w, const float* __restrict__ sp_w,
    const float* __restrict__ csq_w, const float* __restrict__ attn_w,
    unsigned short* __restrict__ rwf, unsigned short* __restrict__ spwf,
    float* __restrict__ rwT, float* __restrict__ cwT, float* __restrict__ awT) {
  int o = blockIdx.x * 256 + threadIdx.x;
  // rwf: 65536
  if (o < 65536) {
    int j = o & 7, r16 = (o >> 3) & 15, quad = (o >> 7) & 3, ks = (o >> 9) & 7, et = o >> 12;
    rwf[o] = f2bf(rel_w[(size_t)(et * 16 + r16) * 256 + ks * 32 + quad * 8 + j]);
    return;
  }
  o -= 65536;
  // spwf: 1179648
  if (o < 1179648) {
    int j = o & 7, r16 = (o >> 3) & 15, quad = (o >> 7) & 3, ks = (o >> 9) & 7;
    int rest = o >> 12;                 // = ((s*16+et)*6 + kc)
    int kc = rest % 6, se = rest / 6;
    int et = se & 15, s = se >> 4;
    spwf[o] = f2bf(sp_w[(size_t)(s * 256 + et * 16 + r16) * 1536 + kc * 256 + ks * 32 + quad * 8 + j]);
    return;
  }
  o -= 1179648;
  if (o < 65536) { int r = o >> 8, e = o & 255; rwT[o] = rel_w[(size_t)e * 256 + r]; return; }
  o -= 65536;
  if (o < 65536) { int r = o >> 8, e = o & 255; cwT[o] = csq_w[(size_t)e * 256 + r]; return; }
  o -= 65536;
  if (o < 196608) {
    int s = o >> 16, rem = o & 65535, ep = rem >> 8, e = rem & 255;
    awT[o] = attn_w[((size_t)s * 256 + e) * 256 + ep];
  }
}

// ---- prep1: qk + sqs -> csl logits -> wts. 2 b's/block, grid 512 ----
__global__ __launch_bounds__(256) void k_prep1(
    const float* __restrict__ r_emb, const float* __restrict__ rwT,
    const float* __restrict__ cwT, const float* __restrict__ csq_b,
    const float* __restrict__ csl_w, const float* __restrict__ csl_b,
    float* __restrict__ qk_ws, float* __restrict__ wts) {
  __shared__ __align__(16) float re[2][256];
  __shared__ float sqs[2][256];
  __shared__ float red[2][3][4];
  int b0 = blockIdx.x * 2;
  int tid = threadIdx.x, lane = tid & 63, wave = tid >> 6;
  int e = tid;
#pragma unroll
  for (int i = 0; i < 2; ++i)
    re[i][tid] = r_emb[(size_t)(b0 + i) * 256 + tid];
  __syncthreads();
  float qkv[2] = {0.f, 0.f}, sv[2] = {0.f, 0.f};
  for (int g = 0; g < 64; ++g) {
    float4 x0 = ((const float4*)re[0])[g];   // LDS broadcast
    float4 x1 = ((const float4*)re[1])[g];
#pragma unroll
    for (int k = 0; k < 4; ++k) {
      int r = g * 4 + k;
      float w = rwT[(size_t)r * 256 + e];    // coalesced
      float c = cwT[(size_t)r * 256 + e];
      float xa = (k == 0) ? x0.x : (k == 1) ? x0.y : (k == 2) ? x0.z : x0.w;
      float xb = (k == 0) ? x1.x : (k == 1) ? x1.y : (k == 2) ? x1.z : x1.w;
      qkv[0] = fmaf(w, xa, qkv[0]); qkv[1] = fmaf(w, xb, qkv[1]);
      sv[0]  = fmaf(c, xa, sv[0]);  sv[1]  = fmaf(c, xb, sv[1]);
    }
  }
  float cb = csq_b[e];
#pragma unroll
  for (int i = 0; i < 2; ++i) {
    qk_ws[(size_t)(b0 + i) * 256 + e] = qkv[i];
    sqs[i][e] = sv[i] + cb;
  }
  __syncthreads();
#pragma unroll
  for (int i = 0; i < 2; ++i)
#pragma unroll
    for (int k = 0; k < 3; ++k) {
      float v = sqs[i][tid] * csl_w[k * 256 + tid];
#pragma unroll
      for (int o = 32; o >= 1; o >>= 1) v += __shfl_xor(v, o, 64);
      if (lane == 0) red[i][k][wave] = v;
    }
  __syncthreads();
  if (tid < 2) {
    int i = tid;
    float l[3];
#pragma unroll
    for (int k = 0; k < 3; ++k)
      l[k] = csl_b[k] + red[i][k][0] + red[i][k][1] + red[i][k][2] + red[i][k][3];
    float m = fmaxf(l[0], fmaxf(l[1], l[2]));
    float e0 = expf(l[0] - m), e1 = expf(l[1] - m), e2 = expf(l[2] - m);
    float inv = 1.f / (e0 + e1 + e2);
    wts[(b0 + i) * 4 + 0] = e0 * inv;
    wts[(b0 + i) * 4 + 1] = e1 * inv;
    wts[(b0 + i) * 4 + 2] = e2 * inv;
  }
}

// ---- prep2: qp = qk @ attn_w^T. 2 b's/block, grid 512 ----
__global__ __launch_bounds__(256) void k_prep2(
    const float* __restrict__ qk_ws, const float* __restrict__ awT,
    float* __restrict__ qp_ws) {
  __shared__ __align__(16) float qk[2][256];
  int b0 = blockIdx.x * 2;
  int tid = threadIdx.x;
  int e = tid;
#pragma unroll
  for (int i = 0; i < 2; ++i)
    qk[i][tid] = qk_ws[(size_t)(b0 + i) * 256 + tid];
  __syncthreads();
  float qpv[3][2];
#pragma unroll
  for (int s = 0; s < 3; ++s) { qpv[s][0] = 0.f; qpv[s][1] = 0.f; }
  for (int g = 0; g < 64; ++g) {
    float4 q0 = ((const float4*)qk[0])[g];
    float4 q1 = ((const float4*)qk[1])[g];
#pragma unroll
    for (int k = 0; k < 4; ++k) {
      int ep = g * 4 + k;
      float xa = (k == 0) ? q0.x : (k == 1) ? q0.y : (k == 2) ? q0.z : q0.w;
      float xb = (k == 0) ? q1.x : (k == 1) ? q1.y : (k == 2) ? q1.z : q1.w;
#pragma unroll
      for (int s = 0; s < 3; ++s) {
        float w = awT[((size_t)s * 256 + ep) * 256 + e];   // coalesced
        qpv[s][0] = fmaf(w, xa, qpv[s][0]);
        qpv[s][1] = fmaf(w, xb, qpv[s][1]);
      }
    }
  }
#pragma unroll
  for (int i = 0; i < 2; ++i)
#pragma unroll
    for (int s = 0; s < 3; ++s)
      qp_ws[((size_t)(b0 + i) * 3 + s) * 256 + e] = qpv[s][i];   // layout [b][s][e]
}

// ---- prep3: t = qp @ rel_w -> t_bf. 2 b's/block, grid 512 ----
__global__ __launch_bounds__(256) void k_prep3(
    const float* __restrict__ qp_ws, const float* __restrict__ rel_w,
    unsigned short* __restrict__ t_bf) {
  __shared__ __align__(16) float qp[2][3][256];
  int b0 = blockIdx.x * 2;
  int tid = threadIdx.x;
  int r = tid;
  for (int j = tid; j < 2 * 3 * 256; j += 256)
    ((float*)qp)[j] = qp_ws[(size_t)b0 * 768 + j];   // contiguous [b][s][e]
  __syncthreads();
  float tacc[3][2];
#pragma unroll
  for (int s = 0; s < 3; ++s) { tacc[s][0] = 0.f; tacc[s][1] = 0.f; }
  for (int e4 = 0; e4 < 64; ++e4) {
    float4 qv[3][2];
#pragma unroll
    for (int s = 0; s < 3; ++s) {
      qv[s][0] = ((const float4*)qp[0][s])[e4];
      qv[s][1] = ((const float4*)qp[1][s])[e4];
    }
#pragma unroll
    for (int j = 0; j < 4; ++j) {
      float w = rel_w[(size_t)(e4 * 4 + j) * 256 + r];   // coalesced
#pragma unroll
      for (int s = 0; s < 3; ++s) {
        float qa = (j == 0) ? qv[s][0].x : (j == 1) ? qv[s][0].y : (j == 2) ? qv[s][0].z : qv[s][0].w;
        float qb = (j == 0) ? qv[s][1].x : (j == 1) ? qv[s][1].y : (j == 2) ? qv[s][1].z : qv[s][1].w;
        tacc[s][0] = fmaf(qa, w, tacc[s][0]);
        tacc[s][1] = fmaf(qb, w, tacc[s][1]);
      }
    }
  }
#pragma unroll
  for (int i = 0; i < 2; ++i)
#pragma unroll
    for (int s = 0; s < 3; ++s)
      t_bf[((size_t)(b0 + i) * 3 + s) * 256 + r] = f2bf(tacc[s][i]);
}

// ------------- K1: Round-1 structure (measured 159 us) — UNCHANGED -------------
__global__ __launch_bounds__(1024, 4) void k1_main(
    const float* __restrict__ nb_rel, const float* __restrict__ delta_t,
    const unsigned char* __restrict__ hm_raw, const float* __restrict__ e_emb,
    const float* __restrict__ p_lt1, const float* __restrict__ p_lt2,
    const float* __restrict__ p_sh, const float* __restrict__ p_lgm,
    const unsigned short* __restrict__ rwf, const unsigned short* __restrict__ t_bf,
    unsigned short* __restrict__ feats) {
  __shared__ __align__(16) struct {
    unsigned int a[NR_ * 132];   // bf16 tile, row stride 264 bf16 (256 data + 8 pad)
    float c[3][NR_];             // unmasked per-scale decay*window weights
    float p[3][NR_];             // logits -> exp scratch
    float nmeta[NR_ * 12];       // [0..2]=mf*c [3]=off(0|1e4) [4..6]=q [7]=mf
  } sm;
  int b = blockIdx.x;
  int tid = threadIdx.x;
  int lane = tid & 63, wave = tid >> 6;
  int row16 = lane & 15, quad = lane >> 4;

  // ---- mask dtype detection: probe first 1024 bytes ----
  int hasNZoff = 0, hasFP = 0;
  {
    unsigned char cc = hm_raw[tid];
    if ((tid & 3) != 0 && cc != 0) {
      hasNZoff = 1;
      if (cc == 0x3Fu || cc == 0x80u) hasFP = 1;
    }
  }
  int cntNZ = __syncthreads_count(hasNZoff);
  int cntFP = __syncthreads_count(hasFP);
  int mmode = (cntNZ == 0) ? 0 : (cntFP > 0 ? 2 : 1);  // 0=int32 1=bool 2=f32

  float tau1 = __expf(p_lt1[0]);
  float tau2 = __expf(p_lt2[0]) + tau1;
  float sharp = fminf(fmaxf(p_sh[0], 0.1f), 5.0f);
  float gamma = __expf(p_lgm[0]);

  bool mk = false;
  if (tid < NR_) {
    float mf = 0.f, c0 = 0.f, c1 = 0.f, c2 = 0.f;
    if (tid < N_) {
      size_t mi = (size_t)b * N_ + tid;
      if (mmode == 0)      mk = ((const int*)hm_raw)[mi] != 0;
      else if (mmode == 1) mk = hm_raw[mi] != 0;
      else                 mk = ((const float*)hm_raw)[mi] != 0.f;
      float dt = delta_t[mi];
      mf = mk ? 1.f : 0.f;
      float decay = __expf(-gamma * fmaxf(dt, 0.f));
      float wf = 1.f / (1.f + __expf(sharp * (dt - tau1)));
      float wc = 1.f / (1.f + __expf(-sharp * (dt - tau2)));
      float wm = fmaxf(1.f - wf - wc, 0.f);
      c0 = decay * wf; c1 = decay * wm; c2 = decay * wc;
    }
    sm.c[0][tid] = c0; sm.c[1][tid] = c1; sm.c[2][tid] = c2;
    f32x4 w0, w1;
    w0[0] = mf * c0; w0[1] = mf * c1; w0[2] = mf * c2; w0[3] = mk ? 0.f : 1e4f;
    w1[0] = 0.f; w1[1] = 0.f; w1[2] = 0.f; w1[3] = mf;
    *(f32x4*)&sm.nmeta[tid * 12]     = w0;
    *(f32x4*)&sm.nmeta[tid * 12 + 4] = w1;
  }
  int cnt = __syncthreads_count(mk ? 1 : 0);
  float nvf = fmaxf((float)cnt, 1.f);
  bool allinv = (cnt == 0);

  // ---- burst staging: issue all 13 loads (MLP=13), then pack to LDS ----
  {
    const float* src = nb_rel + (size_t)b * N_ * 256;
    float4 xs[NT_];
#pragma unroll
    for (int i = 0; i < NT_; ++i) {
      int n = i * 16 + wave;
      int gn = (n < N_) ? n : (N_ - 1);
      xs[i] = *(const float4*)(src + (size_t)gn * 256 + lane * 4);
    }
#pragma unroll
    for (int i = 0; i < NT_; ++i) {
      uint2 pk;
      pk.x = pk_bf(xs[i].x, xs[i].y);
      pk.y = pk_bf(xs[i].z, xs[i].w);
      *(uint2*)&sm.a[(i * 16 + wave) * 132 + lane * 2] = pk;
    }
  }
  __syncthreads();

  // ---- logit dots via MFMA: wave nt computes araw for its 16 rows, 3 scales.
  if (wave < NT_) {
    bf16x8 tfrag[8];
    {
      int sr = (row16 < 3) ? row16 : 0;
      const unsigned short* tb = t_bf + ((size_t)b * 3 + sr) * 256 + quad * 8;
      bf16x8 zer = {0, 0, 0, 0, 0, 0, 0, 0};
#pragma unroll
      for (int ks = 0; ks < 8; ++ks) {
        bf16x8 tv = *(const bf16x8*)(tb + ks * 32);
        tfrag[ks] = (row16 < 3) ? tv : zer;
      }
    }
    f32x4 acc;
#pragma unroll
    for (int cc = 0; cc < 4; ++cc) acc[cc] = 0.f;
#pragma unroll
    for (int ks = 0; ks < 8; ++ks) {
      bf16x8 af = *(const bf16x8*)&sm.a[(wave * 16 + row16) * 132 + ks * 16 + quad * 4];
      acc = __builtin_amdgcn_mfma_f32_16x16x32_bf16(af, tfrag[ks], acc, 0, 0, 0);
    }
    if (row16 < 3) {
#pragma unroll
      for (int rg = 0; rg < 4; ++rg) {
        int n = wave * 16 + quad * 4 + rg;      // C layout: col=lane&15, row=quad*4+rg
        float cw = sm.c[row16][n];
        float mf = sm.nmeta[n * 12 + 7];
        float l = cw * acc[rg] * 0.0625f;
        l = (mf > 0.5f) ? l : -1e4f;
        if (allinv) l = (n < N_) ? 0.f : -1e4f;
        sm.p[row16][n] = l;
      }
    }
  } else if (wave == NT_) {
    // e_emb tail copy overlapped with the dot phase
    for (int i = lane; i < 256; i += 64) {
      unsigned short v = f2bf(e_emb[(size_t)b * 256 + i]);
      feats[((size_t)0 * B_ + b) * K6_ + 1280 + i] = v;
      feats[((size_t)1 * B_ + b) * K6_ + 1280 + i] = v;
      feats[((size_t)2 * B_ + b) * K6_ + 1280 + i] = v;
    }
  }

  // B-fragment preload (wave owns 16 e-cols) — fragment-order rwf, coalesced
  bf16x8 bfr[8];
  {
#pragma unroll
    for (int ks = 0; ks < 8; ++ks)
      bfr[ks] = *(const bf16x8*)(rwf + ((((size_t)wave * 8 + ks) * 4 + quad) * 16 + row16) * 8);
  }
  __syncthreads();

  // ---- softmax (waves 0-2): max -> exp(store back) -> normalize into q ----
  if (wave < 3) {
    int s = wave;
    float m = -1e30f;
    for (int n = lane; n < NR_; n += 64) m = fmaxf(m, sm.p[s][n]);
#pragma unroll
    for (int o = 32; o >= 1; o >>= 1) m = fmaxf(m, __shfl_xor(m, o, 64));
    float ssum = 0.f;
    for (int n = lane; n < NR_; n += 64) {
      float ev = __expf(sm.p[s][n] - m);
      sm.p[s][n] = ev;
      ssum += ev;
    }
#pragma unroll
    for (int o = 32; o >= 1; o >>= 1) ssum += __shfl_xor(ssum, o, 64);
    float inv = 1.f / ssum;
    for (int n = lane; n < NR_; n += 64)
      sm.nmeta[n * 12 + 4 + s] = sm.p[s][n] * inv * sm.c[s][n];
  }
  __syncthreads();

  // ---- MFMA GEMM over 13 n-tiles + register stats (wave owns 16 e-cols) ----
  float s_mean[3], s_mx[3], s_mn[3], s_sq[3], s_av[3];
#pragma unroll
  for (int s = 0; s < 3; ++s) {
    s_mean[s] = 0.f; s_mx[s] = -1e30f; s_mn[s] = 1e30f;
    s_sq[s] = 0.f; s_av[s] = 0.f;
  }

  for (int nt = 0; nt < NT_; ++nt) {
    f32x4 acc;
#pragma unroll
    for (int cc = 0; cc < 4; ++cc) acc[cc] = 0.f;
#pragma unroll
    for (int ks = 0; ks < 8; ++ks) {
      bf16x8 af = *(const bf16x8*)&sm.a[(nt * 16 + row16) * 132 + ks * 16 + quad * 4];
      acc = __builtin_amdgcn_mfma_f32_16x16x32_bf16(af, bfr[ks], acc, 0, 0, 0);
    }
    int nb = nt * 16 + quad * 4;
#pragma unroll
    for (int rg = 0; rg < 4; ++rg) {
      const float* nm = &sm.nmeta[(size_t)(nb + rg) * 12];
      f32x4 w0 = *(const f32x4*)nm;        // cm0 cm1 cm2 off   (broadcast b128)
      f32x4 w1 = *(const f32x4*)(nm + 4);  // q0  q1  q2  mf    (broadcast b128)
      float m = acc[rg];
#pragma unroll
      for (int s = 0; s < 3; ++s) {
        float vm = w0[s] * m;
        s_mean[s] += vm;
        s_mx[s] = fmaxf(s_mx[s], vm);
        s_mn[s] = fminf(s_mn[s], fmaf(w0[s], m, w0[3]));
        float cv = fminf(fmaxf(vm, -10.f), 10.f);
        s_sq[s] = fmaf(cv, cv, s_sq[s]);
        s_av[s] = fmaf(w1[s], m, s_av[s]);
      }
    }
  }

  // ---- reduce across quads, write feats (bf16) ----
#pragma unroll
  for (int s = 0; s < 3; ++s) {
    float vmean = s_mean[s];
    vmean += __shfl_xor(vmean, 16, 64); vmean += __shfl_xor(vmean, 32, 64);
    float vmx = s_mx[s];
    vmx = fmaxf(vmx, __shfl_xor(vmx, 16, 64)); vmx = fmaxf(vmx, __shfl_xor(vmx, 32, 64));
    float vmn = s_mn[s];
    vmn = fminf(vmn, __shfl_xor(vmn, 16, 64)); vmn = fminf(vmn, __shfl_xor(vmn, 32, 64));
    float vsq = s_sq[s];
    vsq += __shfl_xor(vsq, 16, 64); vsq += __shfl_xor(vsq, 32, 64);
    float vav = s_av[s];
    vav += __shfl_xor(vav, 16, 64); vav += __shfl_xor(vav, 32, 64);
    if (lane < 16) {
      int e = wave * 16 + lane;
      size_t base = ((size_t)s * B_ + b) * K6_;
      float meanv = vmean / nvf;
      float stdv = sqrtf(fmaxf(vsq / nvf - meanv * meanv, 1e-6f));
      float mnv = fminf(fmaxf(vmn, -1e4f), 1e4f);
      feats[base + e] = f2bf(meanv);
      feats[base + 256 + e] = f2bf(vmx);
      feats[base + 512 + e] = f2bf(mnv);
      feats[base + 768 + e] = f2bf(stdv);
      feats[base + 1024 + e] = f2bf(vav);
    }
  }
}

// ------- K2: h = feats(bf16) @ sp_w^T + bias -> hbuf (single-stage) — UNCHANGED -------
__global__ __launch_bounds__(256) void k2_kernel(
    const unsigned short* __restrict__ feats, const unsigned short* __restrict__ spwf,
    const float* __restrict__ sp_b, float* __restrict__ hbuf) {
  __shared__ __align__(16) unsigned short A[16][1544];
  int id = blockIdx.x;
  int s = id >> 8;
  int rem = id & 255;
  int b0 = (rem >> 2) * 16;
  int e0 = (rem & 3) * 64;
  int tid = threadIdx.x, lane = tid & 63, wave = tid >> 6;
  int row16 = lane & 15, quad = lane >> 4;

  // burst-stage A: 3072 bf16x8 chunks, 12 per thread
  bf16x8 v[12];
#pragma unroll
  for (int t = 0; t < 12; ++t) {
    int j = tid + t * 256;
    int rw = j / 192, ck = j % 192;
    v[t] = *(const bf16x8*)(feats + ((size_t)s * B_ + b0 + rw) * K6_ + ck * 8);
  }
#pragma unroll
  for (int t = 0; t < 12; ++t) {
    int j = tid + t * 256;
    int rw = j / 192, ck = j % 192;
    *(bf16x8*)&A[rw][ck * 8] = v[t];
  }
  __syncthreads();

  int et = (e0 >> 4) + wave;
  const unsigned short* bp = spwf + (((size_t)s * 16 + et) * 6) * 4096;  // *8ks*4q*16r*8j
  f32x4 acc;
#pragma unroll
  for (int cc = 0; cc < 4; ++cc) acc[cc] = 0.f;
#pragma unroll
  for (int kc = 0; kc < 6; ++kc) {
#pragma unroll
    for (int ks = 0; ks < 8; ++ks) {
      bf16x8 af = *(const bf16x8*)&A[row16][kc * 256 + ks * 32 + quad * 8];
      bf16x8 bf = *(const bf16x8*)(bp + ((size_t)(kc * 8 + ks) * 4 + quad) * 128 + row16 * 8);
      acc = __builtin_amdgcn_mfma_f32_16x16x32_bf16(af, bf, acc, 0, 0, 0);
    }
  }
  {
    int e = e0 + wave * 16 + row16;
    float bias = sp_b[s * 256 + e];
#pragma unroll
    for (int rg = 0; rg < 4; ++rg) {
      int rw = quad * 4 + rg;
      hbuf[((size_t)s * B_ + b0 + rw) * 256 + e] = acc[rg] + bias;
    }
  }
}

// ------- K3: per b: for each s LN+gelu, weighted sum, final LN -> out -------
__global__ __launch_bounds__(256) void k3_kernel(
    const float* __restrict__ hbuf, const float* __restrict__ wts,
    const float* __restrict__ ln_g, const float* __restrict__ ln_b,
    const float* __restrict__ on_g, const float* __restrict__ on_b,
    float* __restrict__ out) {
  __shared__ float rs[4], rq[4];
  int b = blockIdx.x, tid = threadIdx.x, lane = tid & 63, wave = tid >> 6;
  float o = 0.f;
#pragma unroll
  for (int s = 0; s < 3; ++s) {
    float h = hbuf[((size_t)s * B_ + b) * 256 + tid];
    float sum = h, sq = h * h;
#pragma unroll
    for (int off = 32; off >= 1; off >>= 1) {
      sum += __shfl_xor(sum, off, 64);
      sq += __shfl_xor(sq, off, 64);
    }
    if (lane == 0) { rs[wave] = sum; rq[wave] = sq; }
    __syncthreads();
    float ts = rs[0] + rs[1] + rs[2] + rs[3];
    float tq = rq[0] + rq[1] + rq[2] + rq[3];
    __syncthreads();
    float mu = ts * (1.f / 256.f);
    float var = tq * (1.f / 256.f) - mu * mu;
    float rstd = rsqrtf(var + 1e-5f);
    float v = (h - mu) * rstd * ln_g[s * 256 + tid] + ln_b[s * 256 + tid];
    o += wts[b * 4 + s] * gelu_exact(v);
  }
  float sum = o, sq = o * o;
#pragma unroll
  for (int off = 32; off >= 1; off >>= 1) {
    sum += __shfl_xor(sum, off, 64);
    sq += __shfl_xor(sq, off, 64);
  }
  if (lane == 0) { rs[wave] = sum; rq[wave] = sq; }
  __syncthreads();
  float ts = rs[0] + rs[1] + rs[2] + rs[3];
  float tq = rq[0] + rq[1] + rq[2] + rq[3];
  float mu = ts * (1.f / 256.f);
  float var = tq * (1.f / 256.f) - mu * mu;
  float rstd = rsqrtf(var + 1e-5f);
  out[(size_t)b * 256 + tid] = (o - mu) * rstd * on_g[tid] + on_b[tid];
}

extern "C" void kernel_launch(void* const* d_in, const int* in_sizes, int n_in,
                              void* d_out, int out_size, void* d_ws, size_t ws_size,
                              hipStream_t stream) {
  const float* e_emb   = (const float*)d_in[0];
  const float* nb_rel  = (const float*)d_in[1];
  const float* delta_t = (const float*)d_in[2];
  const float* r_emb   = (const float*)d_in[3];
  const unsigned char* hist_mask = (const unsigned char*)d_in[4]; // dtype auto-detected
  const float* rel_w   = (const float*)d_in[5];
  const float* lt1     = (const float*)d_in[6];
  const float* lt2     = (const float*)d_in[7];
  const float* shp     = (const float*)d_in[8];
  const float* lgm     = (const float*)d_in[9];
  const float* attn_w  = (const float*)d_in[10];
  const float* sp_w    = (const float*)d_in[11];
  const float* sp_b    = (const float*)d_in[12];
  const float* ln_g    = (const float*)d_in[13];
  const float* ln_b    = (const float*)d_in[14];
  const float* csq_w   = (const float*)d_in[15];
  const float* csq_b   = (const float*)d_in[16];
  const float* csl_w   = (const float*)d_in[17];
  const float* csl_b   = (const float*)d_in[18];
  const float* on_g    = (const float*)d_in[19];
  const float* on_b    = (const float*)d_in[20];
  float* out = (float*)d_out;

  char* ws = (char*)d_ws;
  unsigned short* rwf   = (unsigned short*)(ws + 0);          // 131072 B (fragment order)
  unsigned short* spwf  = (unsigned short*)(ws + 131072);     // 2359296 B (fragment order)
  unsigned short* t_bf  = (unsigned short*)(ws + 2490368);    // 1572864 B
  float* wts    = (float*)(ws + 4063232);                     // 16 KB
  unsigned short* feats = (unsigned short*)(ws + 4079616);    // 9437184 B
  float* hbuf   = (float*)(ws + 13516800);                    // 3145728 B
  float* rwT    = (float*)(ws + 16662528);                    // 262144 B
  float* cwT    = (float*)(ws + 16924672);                    // 262144 B
  float* awT    = (float*)(ws + 17186816);                    // 786432 B (total ~18.0 MB)

  // Aliased prep intermediates (time-disjoint with their hosts):
  // qk_ws = first 1 MB of feats  (prep1 writes, prep2 reads; k1 rewrites feats after)
  // qp_ws = hbuf (exactly 3145728 B) (prep2 writes, prep3 reads; k2 rewrites hbuf after)
  float* qk_ws = (float*)feats;
  float* qp_ws = hbuf;

  hipLaunchKernelGGL(k_cast, dim3(6144), dim3(256), 0, stream, rel_w, sp_w, csq_w, attn_w,
                     rwf, spwf, rwT, cwT, awT);
  hipLaunchKernelGGL(k_prep1, dim3(512), dim3(256), 0, stream, r_emb, rwT, cwT,
                     csq_b, csl_w, csl_b, qk_ws, wts);
  hipLaunchKernelGGL(k_prep2, dim3(512), dim3(256), 0, stream, qk_ws, awT, qp_ws);
  hipLaunchKernelGGL(k_prep3, dim3(512), dim3(256), 0, stream, qp_ws, rel_w, t_bf);
  hipLaunchKernelGGL(k1_main, dim3(1024), dim3(1024), 0, stream, nb_rel, delta_t, hist_mask,
                     e_emb, lt1, lt2, shp, lgm, rwf, t_bf, feats);
  hipLaunchKernelGGL(k2_kernel, dim3(768), dim3(256), 0, stream, feats, spwf, sp_b, hbuf);
  hipLaunchKernelGGL(k3_kernel, dim3(1024), dim3(256), 0, stream, hbuf, wts, ln_g, ln_b,
                     on_g, on_b, out);
}